// Round 12
// baseline (86.239 us; speedup 1.0000x reference)
//
#include <hip/hip_runtime.h>

// out[n, h*28+w] = cos(pi * x[n,2h,2w] / (m[h,w] + 1e-8)),
// m[h,w] = max_n max(x[n,2h,2w], x[n,2h,2w+1]).
// (Unit-modulus phases + CNOT perm leave the Z0 expectation = cos(t0);
//  params/phases/permutation cancel exactly.)
//
// ONE persistent kernel = R8's fence-free structure with p0 parked in LDS
// (R8's failure was register spills: VGPR_Count=32 for ~130 live floats ->
//  scratch traffic -> 90us. LDS 25.3KB/block removes all spill pressure.)
//  phase 1: 1024 blocks x 8 images; float4 loads of even rows; p0 -> LDS;
//           per-slot maxima -> 4 relaxed agent atomicMax into mu2[b&7][pos].
//  barrier: s_waitcnt vmcnt(0); one agent atomicAdd per block; lane-0 spin on
//           relaxed agent loads. NO __threadfence (R7: = buffer_wbl2 L2 flush).
//  phase 3: max over the 8 mu2 copies (agent loads), cos via v_cos
//           (revolutions), dense float2 stores from LDS.
// Co-residency: 4 blocks/CU needed; LDS cap = 6/CU, launch_bounds(256,4)
// caps VGPR at 128 (kernel ~60) -> all 1024 resident (R8 empirically held).

namespace {

constexpr int IMG   = 3136;        // 56*56 floats / image
constexpr int HW    = 784;         // 28*28 outputs / image
constexpr int NIMG  = 8192;
constexpr int NB    = 1024;
constexpr int IPB   = NIMG / NB;   // 8 images / block
constexpr int NCOPY = 8;           // mu2 slices

#define AGENT __HIP_MEMORY_SCOPE_AGENT

__global__ __launch_bounds__(256, 4)
void k_fused(const float* __restrict__ x, unsigned* __restrict__ mu2,
             unsigned* __restrict__ cnt, float* __restrict__ out)
{
    __shared__ float sp0[IPB][HW + 8];   // 25,344 B; +8 pad keeps rows bank-shifted

    const int t = threadIdx.x;
    const int b = blockIdx.x;

    // float4 slot u covers row 2h, cols 4w..4w+3 = output positions 2u, 2u+1
    const int h0 = t / 14,  w0 = t - h0 * 14,  o0 = h0 * 112 + w0 * 4;
    const int u1 = t + 256;
    const int h1 = u1 / 14, w1 = u1 - h1 * 14, o1 = h1 * 112 + w1 * 4;
    const bool a1 = (u1 < 392);

    float2 lm0 = make_float2(0.f, 0.f), lm1 = make_float2(0.f, 0.f);

    // ---- phase 1: read even rows once; p0 -> LDS; maxima in regs ----
    const float* base = x + (size_t)b * IPB * IMG;
#pragma unroll
    for (int n = 0; n < IPB; ++n) {
        const float* p = base + (size_t)n * IMG;
        float4 v = *(const float4*)(p + o0);
        sp0[n][2 * t]     = v.x;
        sp0[n][2 * t + 1] = v.z;
        lm0.x = fmaxf(lm0.x, fmaxf(v.x, v.y));
        lm0.y = fmaxf(lm0.y, fmaxf(v.z, v.w));
        if (a1) {
            float4 w = *(const float4*)(p + o1);
            sp0[n][2 * u1]     = w.x;
            sp0[n][2 * u1 + 1] = w.z;
            lm1.x = fmaxf(lm1.x, fmaxf(w.x, w.y));
            lm1.y = fmaxf(lm1.y, fmaxf(w.z, w.w));
        }
    }

    // per-slot maxima -> sliced global max (positive floats: uint cmp == float cmp)
    unsigned* row = mu2 + (size_t)(b & (NCOPY - 1)) * HW;
    __hip_atomic_fetch_max(row + 2 * t,     __float_as_uint(lm0.x), __ATOMIC_RELAXED, AGENT);
    __hip_atomic_fetch_max(row + 2 * t + 1, __float_as_uint(lm0.y), __ATOMIC_RELAXED, AGENT);
    if (a1) {
        __hip_atomic_fetch_max(row + 2 * u1,     __float_as_uint(lm1.x), __ATOMIC_RELAXED, AGENT);
        __hip_atomic_fetch_max(row + 2 * u1 + 1, __float_as_uint(lm1.y), __ATOMIC_RELAXED, AGENT);
    }

    // ---- fence-free grid barrier (R8's, validated correct) ----
    asm volatile("s_waitcnt vmcnt(0)" ::: "memory");  // my RMWs performed at IC
    __syncthreads();
    if (t == 0) {
        __hip_atomic_fetch_add(cnt, 1u, __ATOMIC_RELAXED, AGENT);
        while (__hip_atomic_load(cnt, __ATOMIC_RELAXED, AGENT) < (unsigned)NB)
            __builtin_amdgcn_s_sleep(2);
    }
    __syncthreads();

    // ---- phase 3: reduce the 8 copies (agent loads), cos from LDS, store ----
    unsigned m0 = 0, m1 = 0, m2 = 0, m3 = 0;
#pragma unroll
    for (int r = 0; r < NCOPY; ++r) {
        const unsigned* rp = mu2 + (size_t)r * HW;
        m0 = max(m0, __hip_atomic_load(rp + 2 * t,     __ATOMIC_RELAXED, AGENT));
        m1 = max(m1, __hip_atomic_load(rp + 2 * t + 1, __ATOMIC_RELAXED, AGENT));
        if (a1) {
            m2 = max(m2, __hip_atomic_load(rp + 2 * u1,     __ATOMIC_RELAXED, AGENT));
            m3 = max(m3, __hip_atomic_load(rp + 2 * u1 + 1, __ATOMIC_RELAXED, AGENT));
        }
    }
    const float r0 = 0.5f / (__uint_as_float(m0) + 1e-8f);  // cos(pi*u)=v_cos(u/2)
    const float r1 = 0.5f / (__uint_as_float(m1) + 1e-8f);
    const float r2 = 0.5f / (__uint_as_float(m2) + 1e-8f);
    const float r3 = 0.5f / (__uint_as_float(m3) + 1e-8f);

    float* ob = out + (size_t)b * IPB * HW;
#pragma unroll
    for (int n = 0; n < IPB; ++n) {
        float2 oa;
        oa.x = __builtin_amdgcn_cosf(sp0[n][2 * t]     * r0);
        oa.y = __builtin_amdgcn_cosf(sp0[n][2 * t + 1] * r1);
        *(float2*)(ob + (size_t)n * HW + 2 * t) = oa;
        if (a1) {
            float2 ov;
            ov.x = __builtin_amdgcn_cosf(sp0[n][2 * u1]     * r2);
            ov.y = __builtin_amdgcn_cosf(sp0[n][2 * u1 + 1] * r3);
            *(float2*)(ob + (size_t)n * HW + 2 * u1) = ov;
        }
    }
}

} // namespace

extern "C" void kernel_launch(void* const* d_in, const int* in_sizes, int n_in,
                              void* d_out, int out_size, void* d_ws, size_t ws_size,
                              hipStream_t stream) {
    const float* x   = (const float*)d_in[0];
    unsigned*    mu2 = (unsigned*)d_ws;        // 8*784 uints
    unsigned*    cnt = mu2 + NCOPY * HW;       // 1 counter
    float*       out = (float*)d_out;

    hipMemsetAsync(mu2, 0, (NCOPY * HW + 1) * sizeof(unsigned), stream);
    hipLaunchKernelGGL(k_fused, dim3(NB), dim3(256), 0, stream, x, mu2, cnt, out);
}